// Round 1
// baseline (2471.531 us; speedup 1.0000x reference)
//
#include <hip/hip_runtime.h>

// Problem constants: B=4, C=64 (fin=fout), H=W=512, LAT=256
// ws layout (floats):
//   [0    ..  511]  layer0: s[4][64], d[4][64]
//   [512  .. 1023]  layer1: s, d
//   [1024 .. +147456)           wb0[b][co][ci][kk]
//   [1024+147456 .. +147456)    wb1
//   [1024+294912 .. +67108864)  mid[4][64][512][512]
// total = 269,619,200 bytes

#define LRELU_SLOPE 0.2f
#define ACT_GAIN 1.4142135623730951f

__global__ __launch_bounds__(256) void prep_sd_kernel(
    const float* __restrict__ latent,
    const float* __restrict__ w0, const float* __restrict__ mw0, const float* __restrict__ mb0,
    const float* __restrict__ w1, const float* __restrict__ mw1, const float* __restrict__ mb1,
    float* __restrict__ ws)
{
    const int layer = blockIdx.x;
    const float* w  = layer ? w1  : w0;
    const float* mw = layer ? mw1 : mw0;
    const float* mb = layer ? mb1 : mb0;
    float* s_out = ws + layer * 512;
    float* d_out = s_out + 256;

    __shared__ float s_sh[256];
    __shared__ float wsq[4096];

    const int t = threadIdx.x;          // 256 threads
    const int b = t >> 6, c = t & 63;

    // s[b][i] = 1 + mb[i] + sqrt(2/256) * dot(latent[b], mw[i])
    {
        float acc = 0.f;
        const float* lat = latent + b * 256;
        const float* mwr = mw + c * 256;
        for (int l = 0; l < 256; ++l) acc = fmaf(lat[l], mwr[l], acc);
        float s = 1.f + acc * 0.08838834764831845f + mb[c];
        s_sh[t] = s;
        s_out[t] = s;
    }
    // wsq[o][i] = (2/576) * sum_kk w[o][i][kk]^2
    for (int idx = t; idx < 4096; idx += 256) {
        float a = 0.f;
        const float* wr = w + idx * 9;
        #pragma unroll
        for (int k = 0; k < 9; ++k) a = fmaf(wr[k], wr[k], a);
        wsq[idx] = a * (2.0f / 576.0f);
    }
    __syncthreads();
    // d[b][o] = rsqrt( sum_i s[b][i]^2 * wsq[o][i] + eps )
    {
        float a = 0.f;
        const float* sr = s_sh + b * 64;
        const float* qr = wsq + c * 64;
        for (int i = 0; i < 64; ++i) {
            float s = sr[i];
            a = fmaf(s * s, qr[i], a);
        }
        d_out[t] = rsqrtf(a + 1e-5f);
    }
}

// wb[l][b][co][ci][kk] = d[l][b][co] * s[l][b][ci] * sqrt(2/576) * w_l[co][ci][kk]
__global__ __launch_bounds__(256) void prep_wb_kernel(
    const float* __restrict__ w0, const float* __restrict__ w1,
    float* __restrict__ ws)
{
    int idx = blockIdx.x * 256 + threadIdx.x;   // 294912 total
    int layer = idx / 147456;
    int r  = idx - layer * 147456;              // b*36864 + co*576 + ci*9 + kk
    int b  = r / 36864;
    int r2 = r - b * 36864;
    int co = r2 / 576;
    int ci = (r2 / 9) & 63;
    const float* sd = ws + layer * 512;
    const float* w  = layer ? w1 : w0;
    float v = sd[b * 64 + ci] * sd[256 + b * 64 + co] * 0.05892556509887896f * w[r2];
    ws[1024 + layer * 147456 + r] = v;
}

// Plain 3x3 conv with reflect pad(1), per-batch weights wb[b][co][ci][9],
// fused bias + leaky-relu*sqrt(2).
// grid: (8, 32, 16) = (x-tiles of 64, y-tiles of 16, b*4 + co_group)
__global__ __launch_bounds__(256) void conv3x3_kernel(
    const float* __restrict__ in, const float* __restrict__ wb,
    const float* __restrict__ bias, float* __restrict__ out)
{
    __shared__ float lds[18 * 67];  // 66 cols used, stride 67 (2-way bank alias = free)
    const int tx = blockIdx.x * 64;
    const int ty = blockIdx.y * 16;
    const int b  = blockIdx.z >> 2;
    const int co_base = (blockIdx.z & 3) * 16;
    const int t   = threadIdx.x;
    const int row = t >> 4;          // 0..15
    const int x0  = (t & 15) * 4;    // 0..60 step 4

    float acc[16][4];
    #pragma unroll
    for (int i = 0; i < 16; ++i)
        #pragma unroll
        for (int p = 0; p < 4; ++p) acc[i][p] = 0.f;

    for (int ci = 0; ci < 64; ++ci) {
        const float* src = in + (size_t)(b * 64 + ci) * (512 * 512);
        for (int e = t; e < 18 * 66; e += 256) {
            int r = e / 66, c = e - r * 66;
            int gy = ty + r - 1;
            gy = (gy < 0) ? 1 : ((gy > 511) ? 510 : gy);
            int gx = tx + c - 1;
            gx = (gx < 0) ? 1 : ((gx > 511) ? 510 : gx);
            lds[r * 67 + c] = src[gy * 512 + gx];
        }
        __syncthreads();

        float iv[3][6];
        #pragma unroll
        for (int rr = 0; rr < 3; ++rr)
            #pragma unroll
            for (int cc = 0; cc < 6; ++cc)
                iv[rr][cc] = lds[(row + rr) * 67 + x0 + cc];

        // weights: wave-uniform indices -> scalar loads
        const float* wp = wb + ((size_t)(b * 64 + co_base) * 64 + ci) * 9;
        #pragma unroll
        for (int cs = 0; cs < 16; ++cs) {
            const float* wq = wp + cs * 576;
            float w00 = wq[0], w01 = wq[1], w02 = wq[2];
            float w10 = wq[3], w11 = wq[4], w12 = wq[5];
            float w20 = wq[6], w21 = wq[7], w22 = wq[8];
            #pragma unroll
            for (int p = 0; p < 4; ++p) {
                float a = acc[cs][p];
                a = fmaf(w00, iv[0][p],     a);
                a = fmaf(w01, iv[0][p + 1], a);
                a = fmaf(w02, iv[0][p + 2], a);
                a = fmaf(w10, iv[1][p],     a);
                a = fmaf(w11, iv[1][p + 1], a);
                a = fmaf(w12, iv[1][p + 2], a);
                a = fmaf(w20, iv[2][p],     a);
                a = fmaf(w21, iv[2][p + 1], a);
                a = fmaf(w22, iv[2][p + 2], a);
                acc[cs][p] = a;
            }
        }
        __syncthreads();
    }

    #pragma unroll
    for (int cs = 0; cs < 16; ++cs) {
        float bv = bias[co_base + cs];
        float* op = out + ((size_t)(b * 64 + co_base + cs) * 512 + (ty + row)) * 512 + tx + x0;
        #pragma unroll
        for (int p = 0; p < 4; ++p) {
            float v = acc[cs][p] + bv;
            v = (v >= 0.f ? v : LRELU_SLOPE * v) * ACT_GAIN;
            op[p] = v;
        }
    }
}

extern "C" void kernel_launch(void* const* d_in, const int* in_sizes, int n_in,
                              void* d_out, int out_size, void* d_ws, size_t ws_size,
                              hipStream_t stream) {
    const float* x      = (const float*)d_in[0];
    const float* latent = (const float*)d_in[1];
    const float* w0     = (const float*)d_in[2];
    const float* b0     = (const float*)d_in[3];
    const float* mw0    = (const float*)d_in[4];
    const float* mb0    = (const float*)d_in[5];
    const float* w1     = (const float*)d_in[6];
    const float* b1     = (const float*)d_in[7];
    const float* mw1    = (const float*)d_in[8];
    const float* mb1    = (const float*)d_in[9];

    float* ws  = (float*)d_ws;
    float* out = (float*)d_out;
    float* wb0 = ws + 1024;
    float* wb1 = wb0 + 147456;
    float* mid = wb1 + 147456;

    prep_sd_kernel<<<2, 256, 0, stream>>>(latent, w0, mw0, mb0, w1, mw1, mb1, ws);
    prep_wb_kernel<<<1152, 256, 0, stream>>>(w0, w1, ws);

    dim3 grid(8, 32, 16);
    conv3x3_kernel<<<grid, 256, 0, stream>>>(x,   wb0, b0, mid);
    conv3x3_kernel<<<grid, 256, 0, stream>>>(mid, wb1, b1, out);
}

// Round 2
// 1085.934 us; speedup vs baseline: 2.2760x; 2.2760x over previous
//
#include <hip/hip_runtime.h>

// B=4, C=64, H=W=512, LAT=256
// ws layout (bytes):
//   [0, 4096)            sd: layer0 {s[4][64], d[4][64]}, layer1 same (fp32)
//   [4096, 593920)       wT bf16 [l][b][kk][co][ci]  (294912 shorts)
//   [593920, +128MB)     xT bf16 NHWC [b][y][x][ci]
//   [134811648, +128MB)  mid bf16 NHWC
// total 269,029,376 B

typedef __attribute__((ext_vector_type(8))) __bf16 bf16x8;
typedef __attribute__((ext_vector_type(4))) float f32x4;

#define LRELU_SLOPE 0.2f
#define ACT_GAIN 1.4142135623730951f

__device__ __forceinline__ unsigned short f2bf(float f) {
    unsigned u = __builtin_bit_cast(unsigned, f);
    u += 0x7fffu + ((u >> 16) & 1u);   // RNE
    return (unsigned short)(u >> 16);
}
__device__ __forceinline__ float actvn(float v) {
    return (v >= 0.f ? v : LRELU_SLOPE * v) * ACT_GAIN;
}

__global__ __launch_bounds__(256) void prep_sd_kernel(
    const float* __restrict__ latent,
    const float* __restrict__ w0, const float* __restrict__ mw0, const float* __restrict__ mb0,
    const float* __restrict__ w1, const float* __restrict__ mw1, const float* __restrict__ mb1,
    float* __restrict__ sd)
{
    const int layer = blockIdx.x;
    const float* w  = layer ? w1  : w0;
    const float* mw = layer ? mw1 : mw0;
    const float* mb = layer ? mb1 : mb0;
    float* s_out = sd + layer * 512;
    float* d_out = s_out + 256;

    __shared__ float s_sh[256];
    __shared__ float wsq[4096];

    const int t = threadIdx.x;
    const int b = t >> 6, c = t & 63;

    {
        float acc = 0.f;
        const float* lat = latent + b * 256;
        const float* mwr = mw + c * 256;
        for (int l = 0; l < 256; ++l) acc = fmaf(lat[l], mwr[l], acc);
        float s = 1.f + acc * 0.08838834764831845f + mb[c];
        s_sh[t] = s;
        s_out[t] = s;
    }
    for (int idx = t; idx < 4096; idx += 256) {
        float a = 0.f;
        const float* wr = w + idx * 9;
        #pragma unroll
        for (int k = 0; k < 9; ++k) a = fmaf(wr[k], wr[k], a);
        wsq[idx] = a * (2.0f / 576.0f);
    }
    __syncthreads();
    {
        float a = 0.f;
        const float* sr = s_sh + b * 64;
        const float* qr = wsq + c * 64;
        for (int i = 0; i < 64; ++i) {
            float s = sr[i];
            a = fmaf(s * s, qr[i], a);
        }
        d_out[t] = rsqrtf(a + 1e-5f);
    }
}

// wT[l][b][kk][co][ci] = bf16( d*s*wscale * w[co][ci][ky][kx] )
__global__ __launch_bounds__(256) void prep_wbT_kernel(
    const float* __restrict__ w0, const float* __restrict__ w1,
    const float* __restrict__ sd, unsigned short* __restrict__ wT)
{
    int idx = blockIdx.x * 256 + threadIdx.x;   // 294912
    int l  = idx / 147456;
    int r  = idx - l * 147456;
    int b  = r / 36864;
    int r2 = r - b * 36864;                     // kk*4096 + co*64 + ci
    int ci = r2 & 63, co = (r2 >> 6) & 63, kk = r2 >> 12;
    const float* w   = l ? w1 : w0;
    const float* sdl = sd + l * 512;
    float v = sdl[b * 64 + ci] * sdl[256 + b * 64 + co] * 0.05892556509887896f
            * w[(co * 64 + ci) * 9 + kk];
    wT[idx] = f2bf(v);
}

// NCHW fp32 -> NHWC bf16
__global__ __launch_bounds__(256) void transpose_kernel(
    const float* __restrict__ x, unsigned short* __restrict__ xT)
{
    __shared__ unsigned short tl[64 * 72];
    const int b = blockIdx.y;
    const size_t pxbase = (size_t)blockIdx.x * 64;
    const int t = threadIdx.x, px = t & 63, cw = t >> 6;
    const float* src = x + (size_t)b * 64 * 262144;
    #pragma unroll
    for (int i = 0; i < 16; ++i) {
        int ci = cw * 16 + i;
        float v = src[(size_t)ci * 262144 + pxbase + px];
        tl[px * 72 + ci] = f2bf(v);
    }
    __syncthreads();
    unsigned short* dst = xT + ((size_t)b * 262144 + pxbase) * 64;
    #pragma unroll
    for (int j = 0; j < 2; ++j) {
        int idx = t + j * 256;          // 512 chunks: 64 px x 8
        int p2 = idx >> 3, c8 = idx & 7;
        *(uint4*)&dst[(size_t)p2 * 64 + c8 * 8] = *(const uint4*)&tl[p2 * 72 + c8 * 8];
    }
}

// Implicit-GEMM 3x3 conv, reflect pad, bf16 MFMA 16x16x32.
// Block tile: 8 rows x 16 cols x 64 co. 4 waves; wave w -> rows 2w,2w+1.
// grid (32, 64, 4)
template<int OUT_NCHW>
__global__ __launch_bounds__(256, 4) void conv_mfma_kernel(
    const unsigned short* __restrict__ inT,   // [b][y][x][ci] bf16
    const unsigned short* __restrict__ wT,    // [b][kk][co][ci] bf16 (layer slice)
    const float* __restrict__ bias,
    void* __restrict__ outp)
{
    __shared__ unsigned short lds[12960];     // [10][18][72] (ci padded 64->72)
    const int tx0 = blockIdx.x * 16, ty0 = blockIdx.y * 8, b = blockIdx.z;
    const int t = threadIdx.x, wave = t >> 6, lane = t & 63;
    const int col = lane & 15, hi = lane >> 4;

    // ---- stage halo tile (once per block) ----
    const unsigned short* src = inT + (size_t)b * (512 * 512 * 64);
    #pragma unroll
    for (int i = 0; i < 6; ++i) {
        int idx = t + i * 256;
        if (idx < 1440) {                     // 180 positions x 8 chunks
            int pos = idx >> 3, c8 = idx & 7;
            int pr = pos / 18, pc = pos - pr * 18;
            int gy = ty0 + pr - 1; gy = gy < 0 ? 1 : (gy > 511 ? 510 : gy);
            int gx = tx0 + pc - 1; gx = gx < 0 ? 1 : (gx > 511 ? 510 : gx);
            *(uint4*)&lds[pos * 72 + c8 * 8] =
                *(const uint4*)&src[((size_t)(gy * 512 + gx)) * 64 + c8 * 8];
        }
    }
    __syncthreads();

    f32x4 acc[2][4];
    #pragma unroll
    for (int m = 0; m < 2; ++m)
        #pragma unroll
        for (int n = 0; n < 4; ++n) acc[m][n] = (f32x4)(0.f);

    const int r0 = wave * 2;
    const unsigned short* wb = wT + (size_t)b * (9 * 4096);

    #pragma unroll
    for (int kk = 0; kk < 9; ++kk) {
        const int ky = kk / 3, kx = kk - ky * 3;
        const unsigned short* wsft = wb + kk * 4096;
        #pragma unroll
        for (int kc = 0; kc < 2; ++kc) {
            const int kofs = kc * 32 + hi * 8;
            bf16x8 a0 = *(const bf16x8*)&lds[((r0 + ky) * 18 + col + kx) * 72 + kofs];
            bf16x8 a1 = *(const bf16x8*)&lds[((r0 + 1 + ky) * 18 + col + kx) * 72 + kofs];
            #pragma unroll
            for (int n = 0; n < 4; ++n) {
                bf16x8 bw = *(const bf16x8*)&wsft[(n * 16 + col) * 64 + kofs];
                acc[0][n] = __builtin_amdgcn_mfma_f32_16x16x32_bf16(a0, bw, acc[0][n], 0, 0, 0);
                acc[1][n] = __builtin_amdgcn_mfma_f32_16x16x32_bf16(a1, bw, acc[1][n], 0, 0, 0);
            }
        }
    }

    if (OUT_NCHW) {
        // D layout: m(pixel col)=hi*4+reg, n(co)=col -> float4 along x
        float* out = (float*)outp;
        #pragma unroll
        for (int mt = 0; mt < 2; ++mt) {
            int gy = ty0 + r0 + mt;
            #pragma unroll
            for (int n = 0; n < 4; ++n) {
                int co = n * 16 + col;
                float bv = bias[co];
                float4 v;
                v.x = actvn(acc[mt][n][0] + bv);
                v.y = actvn(acc[mt][n][1] + bv);
                v.z = actvn(acc[mt][n][2] + bv);
                v.w = actvn(acc[mt][n][3] + bv);
                *(float4*)&out[((size_t)(b * 64 + co) * 512 + gy) * 512 + tx0 + hi * 4] = v;
            }
        }
    } else {
        // NHWC bf16 out via LDS transpose (per-wave region, reuse input LDS)
        unsigned short* out = (unsigned short*)outp;
        __syncthreads();                       // all waves done reading input tile
        unsigned short* sw = &lds[wave * 2304];  // 32 px x 72
        #pragma unroll
        for (int mt = 0; mt < 2; ++mt)
            #pragma unroll
            for (int n = 0; n < 4; ++n) {
                int co = n * 16 + col;
                float bv = bias[co];
                #pragma unroll
                for (int rg = 0; rg < 4; ++rg) {
                    int px = mt * 16 + hi * 4 + rg;
                    sw[px * 72 + co] = f2bf(actvn(acc[mt][n][rg] + bv));
                }
            }
        __syncthreads();
        #pragma unroll
        for (int j = 0; j < 4; ++j) {
            int idx = lane + j * 64;           // 256 chunks: 32 px x 8
            int px = idx >> 3, c8 = idx & 7;
            int gy = ty0 + r0 + (px >> 4), gx = tx0 + (px & 15);
            *(uint4*)&out[((size_t)b * 262144 + gy * 512 + gx) * 64 + c8 * 8] =
                *(const uint4*)&sw[px * 72 + c8 * 8];
        }
    }
}

extern "C" void kernel_launch(void* const* d_in, const int* in_sizes, int n_in,
                              void* d_out, int out_size, void* d_ws, size_t ws_size,
                              hipStream_t stream) {
    const float* x      = (const float*)d_in[0];
    const float* latent = (const float*)d_in[1];
    const float* w0     = (const float*)d_in[2];
    const float* b0     = (const float*)d_in[3];
    const float* mw0    = (const float*)d_in[4];
    const float* mb0    = (const float*)d_in[5];
    const float* w1     = (const float*)d_in[6];
    const float* b1     = (const float*)d_in[7];
    const float* mw1    = (const float*)d_in[8];
    const float* mb1    = (const float*)d_in[9];

    char* wsb = (char*)d_ws;
    float* sd            = (float*)wsb;                          // 4 KB
    unsigned short* wT   = (unsigned short*)(wsb + 4096);        // 576 KB
    unsigned short* xT   = (unsigned short*)(wsb + 593920);      // 128 MB
    unsigned short* mid  = (unsigned short*)(wsb + 593920 + 134217728);

    prep_sd_kernel<<<2, 256, 0, stream>>>(latent, w0, mw0, mb0, w1, mw1, mb1, sd);
    prep_wbT_kernel<<<1152, 256, 0, stream>>>(w0, w1, sd, wT);
    transpose_kernel<<<dim3(4096, 4), 256, 0, stream>>>(x, xT);

    dim3 grid(32, 64, 4);
    conv_mfma_kernel<0><<<grid, 256, 0, stream>>>(xT, wT, b0, (void*)mid);
    conv_mfma_kernel<1><<<grid, 256, 0, stream>>>(mid, wT + 147456, b1, d_out);
}